// Round 1
// baseline (161.230 us; speedup 1.0000x reference)
//
#include <hip/hip_runtime.h>
#include <stdint.h>

// MemoryEfficientBSpline: out[b,o,p] = sum_i sum_g hat_g(nx[b,i,p]) * coef[b,o,i,g]
// hat_g(nx) = max(0, 1 - |nx - g|),  nx = (clamp(x,-1,1)+1)*2.5 in [0,5], G=6.
// Batched GEMM M=64(o) x N=36864(p) x K=384(i*G) via mfma_f32_16x16x32_f16.
//
// v2 (latency-bound fix): coef is staged to LDS ONCE (full 64x384 f16, g-major,
// one barrier for the whole kernel); x is loaded per-lane directly from global
// (quarter-wave coalesced, L1 absorbs the 2x q8 duplication). The main loop has
// ZERO barriers, so 24-deep load ILP + 3 blocks/CU hide HBM latency instead of
// every wave stalling at per-chunk stage barriers (old: 8 barriers, VALUBusy 24%).

typedef __fp16 half8_t __attribute__((ext_vector_type(8)));
typedef __fp16 half2_t __attribute__((ext_vector_type(2)));
typedef float f32x4 __attribute__((ext_vector_type(4)));

#define NBATCH 8
#define OD 64
#define ID 64
#define PIX 36864          // 192*192
#define NG 6
#define PT 192             // pixels per block tile
#define KI 16              // i per chunk
#define NCHUNK 4           // 4 * 16 = 64 = ID
#define KC (KI * NG)       // 96 k-values per chunk (g-major: k = g*16 + iof)
#define AROW 392           // f16 row stride: 384 used + 8 pad -> 784B rows
                           // (16B-aligned; stride = 196 dw ≡ 4 mod 32 -> 2-way banks, free)
#define PTILES (PIX / PT)  // 192 p-tiles per batch

__global__ __launch_bounds__(256, 3)
void kan_mfma(const float* __restrict__ x, const float* __restrict__ coef,
              float* __restrict__ out) {
  const int t = threadIdx.x;
  const int lane = t & 63;
  const int wave = t >> 6;      // 0..3, owns p sub-range [wave*48, wave*48+48)
  const int q8 = lane >> 4;     // 0..3
  const int col = lane & 15;

  const int bid = blockIdx.x;
  const int b = bid / PTILES;   // same-b blocks contiguous -> coef L2 locality
  const int ptile = bid % PTILES;
  const int p0 = ptile * PT;

  __shared__ __fp16 A_lds[OD][AROW] __attribute__((aligned(16)));

  // ---- stage ALL coef as f16, g-major per 16-i chunk: A[o][c*96 + g*16 + iof] ----
  // thread t: o = t>>2, chunk c = t&3 -> 96 contiguous f32 of coef[b][o][c*16..][g]
  {
    const int o = t >> 2;
    const int c = t & 3;
    const float* crow = coef + (size_t)b * (OD * ID * NG) + o * (ID * NG) + c * KC;
    __fp16* arow = &A_lds[o][c * KC];
#pragma unroll
    for (int blk = 0; blk < 8; ++blk) {  // 2 iof's per blk: src r = iof*6+g, r+6
      f32x4 va = ((const f32x4*)crow)[blk * 3 + 0];
      f32x4 vb = ((const f32x4*)crow)[blk * 3 + 1];
      f32x4 vc = ((const f32x4*)crow)[blk * 3 + 2];
      const float lo[NG] = {va[0], va[1], va[2], va[3], vb[0], vb[1]};
      const float hi[NG] = {vb[2], vb[3], vc[0], vc[1], vc[2], vc[3]};
#pragma unroll
      for (int g = 0; g < NG; ++g) {
        half2_t h2 = __builtin_amdgcn_cvt_pkrtz(lo[g], hi[g]);
        *(half2_t*)&arow[g * KI + blk * 2] = h2;  // 4B-aligned b32 write
      }
    }
  }

  f32x4 acc[4][3];
#pragma unroll
  for (int i = 0; i < 4; ++i)
#pragma unroll
    for (int j = 0; j < 3; ++j)
      acc[i][j] = (f32x4){0.f, 0.f, 0.f, 0.f};

  __syncthreads();  // the ONLY barrier

  const int iof0 = (q8 & 1) * 8;  // which 8 i's this lane's fragment covers
  const int ghalf = q8 >> 1;      // g = 2*ks + ghalf
  const float* xb = x + (size_t)b * ID * PIX + p0 + wave * 48 + col
                      + (size_t)iof0 * PIX;

#pragma unroll
  for (int c = 0; c < NCHUNK; ++c) {
    // ---- per-lane direct x loads: i = c*16 + iof0 + j, p = wave*48 + pti*16 + col ----
    const float* xs = xb + (size_t)(c * KI) * PIX;
    float nxv[3][8];
#pragma unroll
    for (int j = 0; j < 8; ++j) {
      const float* xj = xs + (size_t)j * PIX;
      float a0 = xj[0];
      float a1 = xj[16];
      float a2 = xj[32];
      nxv[0][j] = (fminf(fmaxf(a0, -1.f), 1.f) + 1.f) * 2.5f;
      nxv[1][j] = (fminf(fmaxf(a1, -1.f), 1.f) + 1.f) * 2.5f;
      nxv[2][j] = (fminf(fmaxf(a2, -1.f), 1.f) + 1.f) * 2.5f;
    }

#pragma unroll
    for (int ks = 0; ks < 3; ++ks) {
      half8_t af[4];
#pragma unroll
      for (int ot = 0; ot < 4; ++ot)
        af[ot] = *(const half8_t*)&A_lds[ot * 16 + col][c * KC + ks * 32 + q8 * 8];

      const float gf = (float)(2 * ks + ghalf);
#pragma unroll
      for (int pti = 0; pti < 3; ++pti) {
        union { half2_t h2[4]; half8_t v; } bu;
#pragma unroll
        for (int jj = 0; jj < 4; ++jj) {
          float h0 = fmaxf(0.f, 1.f - fabsf(nxv[pti][2 * jj] - gf));
          float h1 = fmaxf(0.f, 1.f - fabsf(nxv[pti][2 * jj + 1] - gf));
          bu.h2[jj] = __builtin_amdgcn_cvt_pkrtz(h0, h1);
        }
#pragma unroll
        for (int ot = 0; ot < 4; ++ot)
          acc[ot][pti] = __builtin_amdgcn_mfma_f32_16x16x32_f16(
              af[ot], bu.v, acc[ot][pti], 0, 0, 0);
      }
    }
  }

  // ---- epilogue: C row = q8*4 + reg, col = lane&15; out is streamed, never re-read ----
  float* ob = out + (size_t)b * OD * PIX + p0;
#pragma unroll
  for (int ot = 0; ot < 4; ++ot) {
#pragma unroll
    for (int pti = 0; pti < 3; ++pti) {
      int p = wave * 48 + pti * 16 + col;
#pragma unroll
      for (int r = 0; r < 4; ++r) {
        int o = ot * 16 + q8 * 4 + r;
        __builtin_nontemporal_store(acc[ot][pti][r], &ob[(size_t)o * PIX + p]);
      }
    }
  }
}

extern "C" void kernel_launch(void* const* d_in, const int* in_sizes, int n_in,
                              void* d_out, int out_size, void* d_ws, size_t ws_size,
                              hipStream_t stream) {
  const float* x = (const float*)d_in[0];
  const float* coef = (const float*)d_in[1];
  float* out = (float*)d_out;
  dim3 grid(NBATCH * PTILES);
  dim3 block(256);
  hipLaunchKernelGGL(kan_mfma, grid, block, 0, stream, x, coef, out);
}

// Round 2
// 157.158 us; speedup vs baseline: 1.0259x; 1.0259x over previous
//
#include <hip/hip_runtime.h>
#include <stdint.h>

// MemoryEfficientBSpline: out[b,o,p] = sum_i sum_g hat_g(nx[b,i,p]) * coef[b,o,i,g]
// hat_g(nx) = max(0, 1 - |nx - g|),  nx = (clamp(x,-1,1)+1)*2.5 in [0,5], G=6.
// Batched GEMM M=64(o) x N=36864(p) x K=384(i*G) via mfma_f32_16x16x32_f16.
//
// v3: v2 (coef staged to LDS once, zero main-loop barriers, per-lane direct x
// loads) + EXPLICIT cross-chunk register prefetch of x. v2 showed the compiler
// (VGPR_Count=72) never hoisted chunk c+1 loads over chunk c compute, leaving
// ~450-900 cy of L3/HBM latency exposed per chunk (VALUBusy 19.5%, all pipes
// idle). Now: chunk 0's 24 loads issue BEFORE the coef barrier (latency hides
// under staging), and chunk c+1's loads issue at the top of chunk c's compute.
// Also reverts v2's nontemporal stores: they defeated L2 write-combining of the
// 64B quarter-wave segments (WRITE_SIZE 73.9 -> 93.9 MB regression).

typedef __fp16 half8_t __attribute__((ext_vector_type(8)));
typedef __fp16 half2_t __attribute__((ext_vector_type(2)));
typedef float f32x4 __attribute__((ext_vector_type(4)));

#define NBATCH 8
#define OD 64
#define ID 64
#define PIX 36864          // 192*192
#define NG 6
#define PT 192             // pixels per block tile
#define KI 16              // i per chunk
#define NCHUNK 4           // 4 * 16 = 64 = ID
#define KC (KI * NG)       // 96 k-values per chunk (g-major: k = g*16 + iof)
#define AROW 392           // f16 row stride: 384 used + 8 pad -> 784B rows
                           // (16B-aligned; stride = 196 dw ≡ 4 mod 32 -> 2-way banks, free)
#define PTILES (PIX / PT)  // 192 p-tiles per batch

__global__ __launch_bounds__(256, 3)
void kan_mfma(const float* __restrict__ x, const float* __restrict__ coef,
              float* __restrict__ out) {
  const int t = threadIdx.x;
  const int lane = t & 63;
  const int wave = t >> 6;      // 0..3, owns p sub-range [wave*48, wave*48+48)
  const int q8 = lane >> 4;     // 0..3
  const int col = lane & 15;

  const int bid = blockIdx.x;
  const int b = bid / PTILES;   // same-b blocks contiguous -> coef L2 locality
  const int ptile = bid % PTILES;
  const int p0 = ptile * PT;

  __shared__ __fp16 A_lds[OD][AROW] __attribute__((aligned(16)));

  const int iof0 = (q8 & 1) * 8;  // which 8 i's this lane's fragment covers
  const int ghalf = q8 >> 1;      // g = 2*ks + ghalf
  const float* xb = x + (size_t)b * ID * PIX + p0 + wave * 48 + col
                      + (size_t)iof0 * PIX;

  // ---- issue chunk 0's x loads FIRST: latency hides under coef staging ----
  float xcur[24];
#pragma unroll
  for (int j = 0; j < 8; ++j) {
    const float* xj = xb + (size_t)j * PIX;
    xcur[j * 3 + 0] = xj[0];
    xcur[j * 3 + 1] = xj[16];
    xcur[j * 3 + 2] = xj[32];
  }

  // ---- stage ALL coef as f16, g-major per 16-i chunk: A[o][c*96 + g*16 + iof] ----
  // thread t: o = t>>2, chunk c = t&3 -> 96 contiguous f32 of coef[b][o][c*16..][g]
  {
    const int o = t >> 2;
    const int c = t & 3;
    const float* crow = coef + (size_t)b * (OD * ID * NG) + o * (ID * NG) + c * KC;
    __fp16* arow = &A_lds[o][c * KC];
#pragma unroll
    for (int blk = 0; blk < 8; ++blk) {  // 2 iof's per blk: src r = iof*6+g, r+6
      f32x4 va = ((const f32x4*)crow)[blk * 3 + 0];
      f32x4 vb = ((const f32x4*)crow)[blk * 3 + 1];
      f32x4 vc = ((const f32x4*)crow)[blk * 3 + 2];
      const float lo[NG] = {va[0], va[1], va[2], va[3], vb[0], vb[1]};
      const float hi[NG] = {vb[2], vb[3], vc[0], vc[1], vc[2], vc[3]};
#pragma unroll
      for (int g = 0; g < NG; ++g) {
        half2_t h2 = __builtin_amdgcn_cvt_pkrtz(lo[g], hi[g]);
        *(half2_t*)&arow[g * KI + blk * 2] = h2;  // 4B-aligned b32 write
      }
    }
  }

  f32x4 acc[4][3];
#pragma unroll
  for (int i = 0; i < 4; ++i)
#pragma unroll
    for (int j = 0; j < 3; ++j)
      acc[i][j] = (f32x4){0.f, 0.f, 0.f, 0.f};

  __syncthreads();  // the ONLY barrier

#pragma unroll
  for (int c = 0; c < NCHUNK; ++c) {
    // ---- prefetch chunk c+1's x into registers (overlaps this chunk's compute) ----
    float xnext[24];
    if (c + 1 < NCHUNK) {
      const float* xs = xb + (size_t)((c + 1) * KI) * PIX;
#pragma unroll
      for (int j = 0; j < 8; ++j) {
        const float* xj = xs + (size_t)j * PIX;
        xnext[j * 3 + 0] = xj[0];
        xnext[j * 3 + 1] = xj[16];
        xnext[j * 3 + 2] = xj[32];
      }
    }

    // ---- nx for my 24 (p, i) pairs ----
    float nxv[3][8];
#pragma unroll
    for (int j = 0; j < 8; ++j) {
#pragma unroll
      for (int pt = 0; pt < 3; ++pt)
        nxv[pt][j] = (fminf(fmaxf(xcur[j * 3 + pt], -1.f), 1.f) + 1.f) * 2.5f;
    }

#pragma unroll
    for (int ks = 0; ks < 3; ++ks) {
      half8_t af[4];
#pragma unroll
      for (int ot = 0; ot < 4; ++ot)
        af[ot] = *(const half8_t*)&A_lds[ot * 16 + col][c * KC + ks * 32 + q8 * 8];

      const float gf = (float)(2 * ks + ghalf);
#pragma unroll
      for (int pti = 0; pti < 3; ++pti) {
        union { half2_t h2[4]; half8_t v; } bu;
#pragma unroll
        for (int jj = 0; jj < 4; ++jj) {
          float h0 = fmaxf(0.f, 1.f - fabsf(nxv[pti][2 * jj] - gf));
          float h1 = fmaxf(0.f, 1.f - fabsf(nxv[pti][2 * jj + 1] - gf));
          bu.h2[jj] = __builtin_amdgcn_cvt_pkrtz(h0, h1);
        }
#pragma unroll
        for (int ot = 0; ot < 4; ++ot)
          acc[ot][pti] = __builtin_amdgcn_mfma_f32_16x16x32_f16(
              af[ot], bu.v, acc[ot][pti], 0, 0, 0);
      }
    }

    if (c + 1 < NCHUNK) {
#pragma unroll
      for (int k = 0; k < 24; ++k) xcur[k] = xnext[k];
    }
  }

  // ---- epilogue: C row = q8*4 + reg, col = lane&15 (plain stores: L2 merges) ----
  float* ob = out + (size_t)b * OD * PIX + p0;
#pragma unroll
  for (int ot = 0; ot < 4; ++ot) {
#pragma unroll
    for (int pti = 0; pti < 3; ++pti) {
      int p = wave * 48 + pti * 16 + col;
#pragma unroll
      for (int r = 0; r < 4; ++r) {
        int o = ot * 16 + q8 * 4 + r;
        ob[(size_t)o * PIX + p] = acc[ot][pti][r];
      }
    }
  }
}

extern "C" void kernel_launch(void* const* d_in, const int* in_sizes, int n_in,
                              void* d_out, int out_size, void* d_ws, size_t ws_size,
                              hipStream_t stream) {
  const float* x = (const float*)d_in[0];
  const float* coef = (const float*)d_in[1];
  float* out = (float*)d_out;
  dim3 grid(NBATCH * PTILES);
  dim3 block(256);
  hipLaunchKernelGGL(kan_mfma, grid, block, 0, stream, x, coef, out);
}